// Round 13
// baseline (184.998 us; speedup 1.0000x reference)
//
#include <hip/hip_runtime.h>
#include <hip/hip_bf16.h>

// Problem constants
constexpr int B  = 2;
constexpr int S  = 2048;
constexpr int E  = 1024;
constexpr int H  = 16;
constexpr int DK = 64;
constexpr int M  = B * S;            // 4096 rows of x
constexpr int N3 = 3 * E;            // stacked [Wk; Wv; Wq]
constexpr long RSZ = (long)B * H * S * DK;  // one output region (4.19M elems)

// Q scale: 1/sqrt(DK) * log2(e) -> softmax via raw v_exp_f32 (base-2), no mul.
#define QSCALE 0.18033688011112042f

using bf16x8 = __attribute__((ext_vector_type(8))) __bf16;
using bf16x4 = __attribute__((ext_vector_type(4))) __bf16;
using f32x4  = __attribute__((ext_vector_type(4))) float;

// async global->LDS, 16B/lane; LDS base wave-uniform, lane i lands at +i*16 B.
__device__ __forceinline__ void async16(__bf16* lds, const __bf16* g) {
    __builtin_amdgcn_global_load_lds(
        (const __attribute__((address_space(1))) void*)g,
        (__attribute__((address_space(3))) void*)lds, 16, 0, 0);
}
__device__ __forceinline__ void async16f(float* lds, const float* g) {
    __builtin_amdgcn_global_load_lds(
        (const __attribute__((address_space(1))) void*)g,
        (__attribute__((address_space(3))) void*)lds, 16, 0, 0);
}

__device__ __forceinline__ bf16x8 cvt8(f32x4 lo, f32x4 hi) {
    bf16x8 r;
    r[0] = (__bf16)lo[0]; r[1] = (__bf16)lo[1];
    r[2] = (__bf16)lo[2]; r[3] = (__bf16)lo[3];
    r[4] = (__bf16)hi[0]; r[5] = (__bf16)hi[1];
    r[6] = (__bf16)hi[2]; r[7] = (__bf16)hi[3];
    return r;
}

// ---------------- QKV GEMM v8: fp32-direct DMA staging (cvt fused, 2 launches) ----------------
// R12 accounting: 3 dispatch gaps ~18us each = ~54us of the 169.5 wall; the
// R11 cooperative fusion failed on cross-XCD staleness of the SHARED xb/wall
// intermediate. v8 needs NO inter-block communication: each block DMA-stages
// its fp32 x/W panels directly (global_load_lds, same (lane&7)^sr chunk XOR
// as the verified attn staging) and converts to bf16 at fragment-read time.
// No cvt kernel, no xb/wall, no d_out scratch. fp32 tiles double LDS bytes ->
// double-buffer 64 KB, distance-1 (loads get a full iter of lead, in flight
// across the raw barrier), 2 blocks/CU. Frag-read bank shape identical to the
// verified bf16 m97 pattern (8 lanes per 4-bank group = b128 service rate).
// MFMA core / epilogues / theta path byte-identical to R10-verified code.
__global__ __launch_bounds__(256, 2)
void qkv_fused(const float* __restrict__ x, const float* __restrict__ Wk,
               const float* __restrict__ Wv, const float* __restrict__ Wq,
               const float* __restrict__ theta, __bf16* __restrict__ kvq) {
    __shared__ __align__(1024) float smemf[4 * 4096];   // A0|A1|B0|B1 fp32 = 64 KB
    __bf16* tile = (__bf16*)smemf;   // epilogue alias: V 32 KB / K,Q 33 KB

    const int t    = threadIdx.x;
    const int lane = t & 63;
    const int w    = t >> 6;
    const int quad = lane >> 4;
    const int l16  = lane & 15;
    const int wm   = w >> 1, wn = w & 1;      // 2x2 wave grid, 64x64 each

    // 2D XCD-locality remap (R9: neutral but harmless; grid = 768 blocks)
    const int id   = blockIdx.x;
    const int xcd  = id & 7;
    const int lid  = id >> 3;
    const int lr   = lid / 12, lc0 = lid % 12;
    const int mbase = ((xcd >> 1) * 8 + lr) * 128;
    const int nbase = ((xcd & 1) * 12 + lc0) * 128;

    const int region = nbase >> 10;           // block-uniform 0=K 1=V 2=Q
    const float* wsel = region == 0 ? Wk : region == 1 ? Wv : Wq;
    const int nbw = nbase & 1023;

    f32x4 acc[4][4];
    #pragma unroll
    for (int i = 0; i < 4; i++)
        #pragma unroll
        for (int j = 0; j < 4; j++)
            acc[i][j] = f32x4{0.f, 0.f, 0.f, 0.f};

    // staging: 8 rows x 8 chunks(16B = 4 f32) per async16; chunk XOR-swizzled
    // at source so LDS phys chunk p of row r holds logical chunk p^(r&7).
    const int sr  = lane >> 3;
    const int scs = (lane & 7) ^ sr;

    auto stage = [&](int buf, int kk) {       // kk in f32 elements
        #pragma unroll
        for (int i = 0; i < 4; i++) {
            const int rb = w * 32 + i * 8;
            async16f(smemf + buf * 4096 + rb * 32,
                     x + (long)(mbase + rb + sr) * E + kk + scs * 4);
            async16f(smemf + 8192 + buf * 4096 + rb * 32,
                     wsel + (long)(nbw + rb + sr) * E + kk + scs * 4);
        }
    };

    stage(0, 0);                              // prologue: tile 0 (8 issues/wave)

    const int sw8 = l16 & 7;
    int cur = 0;
    constexpr int ITERS = E / 32;   // 32
    for (int it = 0; it < ITERS; it++) {
        // only this tile's 8 loads/wave outstanding -> exact drain
        asm volatile("s_waitcnt vmcnt(0)" ::: "memory");
        asm volatile("s_barrier" ::: "memory");   // raw: no lgkm drain

        if (it + 1 < ITERS) stage(cur ^ 1, (it + 1) * 32);

        const float* Af = smemf + cur * 4096;
        const float* Bf = smemf + 8192 + cur * 4096;
        bf16x8 a[4], b[4];
        #pragma unroll
        for (int i = 0; i < 4; i++) {
            const int row = wm * 64 + i * 16 + l16;
            f32x4 lo = *reinterpret_cast<const f32x4*>(
                &Af[row * 32 + (((2 * quad) ^ sw8) * 4)]);
            f32x4 hi = *reinterpret_cast<const f32x4*>(
                &Af[row * 32 + (((2 * quad + 1) ^ sw8) * 4)]);
            a[i] = cvt8(lo, hi);
        }
        #pragma unroll
        for (int j = 0; j < 4; j++) {
            const int row = wn * 64 + j * 16 + l16;
            f32x4 lo = *reinterpret_cast<const f32x4*>(
                &Bf[row * 32 + (((2 * quad) ^ sw8) * 4)]);
            f32x4 hi = *reinterpret_cast<const f32x4*>(
                &Bf[row * 32 + (((2 * quad + 1) ^ sw8) * 4)]);
            b[j] = cvt8(lo, hi);
        }
        #pragma unroll
        for (int i = 0; i < 4; i++)
            #pragma unroll
            for (int j = 0; j < 4; j++)
                acc[i][j] = __builtin_amdgcn_mfma_f32_16x16x32_bf16(a[i], b[j], acc[i][j], 0, 0, 0);

        cur ^= 1;
    }

    // ---- epilogues: R10-verified, unchanged ----
    const int bb = mbase >> 11;
    __syncthreads();                          // drain staging reads before aliasing smem
    if (region == 1) {
        // ---- V: transposed tile -> V^T [B,H,DK,S] ----
        #pragma unroll
        for (int i = 0; i < 4; i++) {
            const int cchunk = wm * 8 + i * 2 + (quad >> 1);
            #pragma unroll
            for (int j = 0; j < 4; j++) {
                const int cirb = wn * 64 + j * 16 + l16;
                const int cs = cchunk ^ l16;
                bf16x4 pk;
                #pragma unroll
                for (int r = 0; r < 4; r++) pk[r] = (__bf16)acc[i][j][r];
                *reinterpret_cast<bf16x4*>(&tile[cirb * 128 + cs * 8 + (quad & 1) * 4]) = pk;
            }
        }
        __syncthreads();
        const int h0 = nbw >> 6;
        __bf16* vt = kvq + RSZ;               // V^T region: [B,H,DK,S]
        #pragma unroll
        for (int p = 0; p < 8; p++) {
            const int dcol = p * 16 + (t >> 4);
            const int lc = t & 15;
            const int cs2 = lc ^ (dcol & 15);
            bf16x8 vv = *reinterpret_cast<const bf16x8*>(&tile[dcol * 128 + cs2 * 8]);
            const int hh = h0 + (dcol >> 6), d = dcol & 63;
            *reinterpret_cast<bf16x8*>(
                &vt[((long)(bb * H + hh) * DK + d) * S + (mbase & 2047) + lc * 8]) = vv;
        }
    } else {
        // ---- K/Q: [s][d] tile (stride 132) -> coalesced 16B stores ----
        __bf16* dst = kvq + (region == 2 ? 2 * RSZ : 0);
        float th[4];
        if (region == 2) {
            #pragma unroll
            for (int j = 0; j < 4; j++) th[j] = theta[j * 16 + l16];
        }
        #pragma unroll
        for (int i = 0; i < 4; i++) {
            #pragma unroll
            for (int j = 0; j < 4; j++) {
                const int c = wn * 64 + j * 16 + l16;
                #pragma unroll
                for (int r = 0; r < 4; r++) {
                    const int cir = wm * 64 + i * 16 + quad * 4 + r;
                    float v = acc[i][j][r];
                    if (region == 2) v = cosf(v + th[j]) * QSCALE;  // fold 1/sqrt(DK)*log2e
                    tile[cir * 132 + c] = (__bf16)v;
                }
            }
        }
        __syncthreads();
        const int h0 = nbw >> 6;
        #pragma unroll
        for (int p = 0; p < 8; p++) {
            const int row = p * 16 + (t >> 4);   // 0..127 (within-block s)
            const int lc  = t & 15;              // 8-elem chunk along d
            bf16x8 vv = *reinterpret_cast<const bf16x8*>(&tile[row * 132 + lc * 8]);
            const int s = (mbase + row) & 2047;
            const int h = h0 + (lc >> 3), d = (lc & 7) * 8;
            *reinterpret_cast<bf16x8*>(
                &dst[((long)(bb * H + h) * S + s) * DK + d]) = vv;
        }
    }
}

// ---------------- attention v15 (R12-verified 53.1-53.3us) ----------------
// v10 loop + coalesced epilogue (neutral but verified). Kept verbatim.
__global__ __launch_bounds__(256, 2)
void attn_kernel(const __bf16* __restrict__ q_ws, const __bf16* __restrict__ k_ws,
                 const __bf16* __restrict__ v_ws, float* __restrict__ out) {
    __shared__ __align__(1024) __bf16 Ks[3][64 * 64];   // [key][d] swizzled, 8 KB each
    __shared__ __align__(1024) __bf16 Vs[3][64 * 64];   // [d][key] swizzled, 8 KB each
    __shared__ __align__(16)   __bf16 Pl[4][32 * 72];   // per-wave P [qrow][key], stride 72
    __shared__ __align__(16)   float  ls_lds[4][32];

    const int lane = threadIdx.x & 63;
    const int w    = threadIdx.x >> 6;          // 0..3
    const int quad = lane >> 4;
    const int l16  = lane & 15;

    // XCD swizzle: 4 bh per id%8 class -> per-XCD K/V set 2MB < 4MB L2 (R6-verified)
    const int id    = blockIdx.x;
    const int bh    = (id & 7) + 8 * ((id >> 3) & 3);
    const int qbase = (id >> 5) * 128 + w * 32;  // wave owns 32 q-rows

    const __bf16* qp = q_ws + (long)bh * S * DK;
    const __bf16* kp = k_ws + (long)bh * S * DK;
    const __bf16* vp = v_ws + (long)bh * DK * S;   // [DK][S]

    // staging: 8 rows x 8 chunks(16B) per async16; source chunk XOR-swizzled
    const int sr  = lane >> 3;
    const int scs = (lane & 7) ^ sr;

    // Q B-frags resident: B[k=d=ks*32+quad*8+j][n=qrow=nt*16+l16]
    bf16x8 bq[2][2];
    #pragma unroll
    for (int nt = 0; nt < 2; nt++)
        #pragma unroll
        for (int ks = 0; ks < 2; ks++)
            bq[nt][ks] = *reinterpret_cast<const bf16x8*>(
                qp + (long)(qbase + nt * 16 + l16) * DK + ks * 32 + quad * 8);

    f32x4 o[2][4];     // O[qrow-tile mt][d-tile nt]
    #pragma unroll
    for (int i = 0; i < 2; i++)
        #pragma unroll
        for (int j = 0; j < 4; j++) o[i][j] = f32x4{0.f, 0.f, 0.f, 0.f};
    float lsum[2] = {0.f, 0.f};   // per-lane partial row sums, qrow = nt*16+l16

    // prologue: tiles 0,1 into buffers 0,1 — 4 DMA issues per tile per wave
    #pragma unroll
    for (int pt = 0; pt < 2; pt++) {
        #pragma unroll
        for (int i = 0; i < 2; i++) {
            const int row = w * 16 + i * 8;
            async16(&Ks[pt][row * 64], kp + (long)(pt * 64 + row + sr) * DK + scs * 8);
            async16(&Vs[pt][row * 64], vp + (long)(row + sr) * S + pt * 64 + scs * 8);
        }
    }

    int cur = 0;
    constexpr int ITERS = S / 64;   // 32
    for (int it = 0; it < ITERS; it++) {
        if (it < ITERS - 1) asm volatile("s_waitcnt vmcnt(4)" ::: "memory");
        else                asm volatile("s_waitcnt vmcnt(0)" ::: "memory");
        asm volatile("s_barrier" ::: "memory");   // raw: no drain

        if (it + 2 < ITERS) {
            const int kt2 = (it + 2) * 64;
            const int pb  = (cur == 0) ? 2 : cur - 1;
            #pragma unroll
            for (int i = 0; i < 2; i++) {
                const int row = w * 16 + i * 8;
                async16(&Ks[pb][row * 64], kp + (long)(kt2 + row + sr) * DK + scs * 8);
                async16(&Vs[pb][row * 64], vp + (long)(row + sr) * S + kt2 + scs * 8);
            }
        }

        // ---- S^T = K Q^T : C[key(regs) 64][qrow(lanes) 32] ----
        f32x4 sacc[4][2];  // [key-tile mt][qrow-tile nt]
        #pragma unroll
        for (int i = 0; i < 4; i++)
            #pragma unroll
            for (int j = 0; j < 2; j++) sacc[i][j] = f32x4{0.f, 0.f, 0.f, 0.f};
        #pragma unroll
        for (int ks = 0; ks < 2; ks++) {
            bf16x8 ak[4];
            #pragma unroll
            for (int mt = 0; mt < 4; mt++)
                ak[mt] = *reinterpret_cast<const bf16x8*>(
                    &Ks[cur][(mt * 16 + l16) * 64 + ((ks * 4 + quad) ^ (l16 & 7)) * 8]);
            #pragma unroll
            for (int mt = 0; mt < 4; mt++)
                #pragma unroll
                for (int nt = 0; nt < 2; nt++)
                    sacc[mt][nt] = __builtin_amdgcn_mfma_f32_16x16x32_bf16(
                        ak[mt], bq[nt][ks], sacc[mt][nt], 0, 0, 0);
        }

        // ---- P = exp2(S^T): 4 consecutive keys (regs) -> one b64 store ----
        #pragma unroll
        for (int mt = 0; mt < 4; mt++)
            #pragma unroll
            for (int nt = 0; nt < 2; nt++) {
                float p0 = __builtin_amdgcn_exp2f(sacc[mt][nt][0]);
                float p1 = __builtin_amdgcn_exp2f(sacc[mt][nt][1]);
                float p2 = __builtin_amdgcn_exp2f(sacc[mt][nt][2]);
                float p3 = __builtin_amdgcn_exp2f(sacc[mt][nt][3]);
                lsum[nt] += (p0 + p1) + (p2 + p3);
                bf16x4 pk;
                pk[0] = (__bf16)p0; pk[1] = (__bf16)p1;
                pk[2] = (__bf16)p2; pk[3] = (__bf16)p3;
                *reinterpret_cast<bf16x4*>(
                    &Pl[w][(nt * 16 + l16) * 72 + mt * 16 + quad * 4]) = pk;
            }

        // ---- O += P V : A=P[m=qrow][k=key], B=V[k=key][n=d], 2 k-halves ----
        #pragma unroll
        for (int kh = 0; kh < 2; kh++) {
            bf16x8 bv[4];
            #pragma unroll
            for (int nt = 0; nt < 4; nt++)
                bv[nt] = *reinterpret_cast<const bf16x8*>(
                    &Vs[cur][(nt * 16 + l16) * 64 + ((kh * 4 + quad) ^ (l16 & 7)) * 8]);
            #pragma unroll
            for (int mt = 0; mt < 2; mt++) {
                bf16x8 ap = *reinterpret_cast<const bf16x8*>(
                    &Pl[w][(mt * 16 + l16) * 72 + kh * 32 + quad * 8]);
                #pragma unroll
                for (int nt = 0; nt < 4; nt++)
                    o[mt][nt] = __builtin_amdgcn_mfma_f32_16x16x32_bf16(
                        ap, bv[nt], o[mt][nt], 0, 0, 0);
            }
        }

        cur = (cur == 2) ? 0 : cur + 1;
    }

    // ---- finalize l: reduce partials across the 4 quads, broadcast via LDS ----
    #pragma unroll
    for (int nt = 0; nt < 2; nt++) {
        float v = lsum[nt];
        v += __shfl_xor(v, 16);
        v += __shfl_xor(v, 32);
        ls_lds[w][nt * 16 + l16] = v;   // quads duplicate-write same value (benign)
    }

    // ---- epilogue: per-wave LDS bounce -> coalesced f32x4 stores ----
    __syncthreads();   // all waves done reading Ks/Vs (loop fully consumed)
    float* scr = (w < 3) ? (float*)&Ks[w][0] : (float*)&Vs[0][0];  // 8 KB = 32x64 f32
    const int b = bh >> 4, h = bh & 15;
    #pragma unroll
    for (int mt = 0; mt < 2; mt++) {
        f32x4 lv = *reinterpret_cast<const f32x4*>(&ls_lds[w][mt * 16 + quad * 4]);
        #pragma unroll
        for (int r = 0; r < 4; r++) {
            const float inv = 1.0f / lv[r];
            const int row = mt * 16 + quad * 4 + r;       // 0..31 within wave
            #pragma unroll
            for (int nt = 0; nt < 4; nt++)
                scr[row * 64 + nt * 16 + l16] = o[mt][nt][r] * inv;
        }
    }
    __syncthreads();   // order scr writes before aliased reads
    #pragma unroll
    for (int p = 0; p < 8; p++) {
        const int c = p * 64 + lane;
        const int row = c >> 4, chunk = c & 15;           // row 0..31, 16B chunk 0..15
        f32x4 v4 = *reinterpret_cast<const f32x4*>(&scr[row * 64 + chunk * 4]);
        const int srow = qbase + row;
        *reinterpret_cast<f32x4*>(
            &out[(long)(b * S + srow) * E + h * DK + chunk * 4]) = v4;
    }
}

extern "C" void kernel_launch(void* const* d_in, const int* in_sizes, int n_in,
                              void* d_out, int out_size, void* d_ws, size_t ws_size,
                              hipStream_t stream) {
    const float* x     = (const float*)d_in[0];
    const float* Wk    = (const float*)d_in[1];
    const float* Wv    = (const float*)d_in[2];
    const float* Wq    = (const float*)d_in[3];
    const float* theta = (const float*)d_in[4];
    float* out = (float*)d_out;

    // ws: kvq[3*RSZ: K | V^T | Q] -- 25.2 MB. No other intermediates: qkv
    // stages fp32 x/W directly per-block (no cvt kernel, no xb/wall).
    __bf16* kvq  = (__bf16*)d_ws;
    __bf16* k_ws = kvq;
    __bf16* v_t  = kvq + RSZ;
    __bf16* q_ws = kvq + 2 * RSZ;

    dim3 blk(256);
    qkv_fused<<<dim3(768), blk, 0, stream>>>(x, Wk, Wv, Wq, theta, kvq);
    attn_kernel<<<dim3(512), blk, 0, stream>>>(q_ws, k_ws, v_t, out);
}

// Round 14
// 167.702 us; speedup vs baseline: 1.1031x; 1.1031x over previous
//
#include <hip/hip_runtime.h>
#include <hip/hip_bf16.h>

// Problem constants
constexpr int B  = 2;
constexpr int S  = 2048;
constexpr int E  = 1024;
constexpr int H  = 16;
constexpr int DK = 64;
constexpr int M  = B * S;            // 4096 rows of x
constexpr int N3 = 3 * E;            // stacked [Wk; Wv; Wq]
constexpr long RSZ = (long)B * H * S * DK;  // one output region (4.19M elems)

// Q scale: 1/sqrt(DK) * log2(e) -> softmax via raw v_exp_f32 (base-2), no mul.
#define QSCALE 0.18033688011112042f

using bf16x8 = __attribute__((ext_vector_type(8))) __bf16;
using bf16x4 = __attribute__((ext_vector_type(4))) __bf16;
using f32x4  = __attribute__((ext_vector_type(4))) float;

// async global->LDS, 16B/lane; LDS base wave-uniform, lane i lands at +i*16 B.
__device__ __forceinline__ void async16(__bf16* lds, const __bf16* g) {
    __builtin_amdgcn_global_load_lds(
        (const __attribute__((address_space(1))) void*)g,
        (__attribute__((address_space(3))) void*)lds, 16, 0, 0);
}

// ---------------- cvt: x and stacked W's -> bf16 (into d_out scratch) ----------------
// R13 post-mortem: fp32-staged fusion (v8) hit 100-103us (distance-1 drain +
// fp32 L2 thrash); reverted to the R10-proven bf16 3-kernel structure.
// cvt now grid-stride: 1792 blocks x 256 thr x 4 float4 = exact cover (G11).
__global__ __launch_bounds__(256)
void cvt_kernel(const float* __restrict__ x, const float* __restrict__ Wk,
                const float* __restrict__ Wv, const float* __restrict__ Wq,
                __bf16* __restrict__ xb, __bf16* __restrict__ wall) {
    const long total4 = ((long)M * E + (long)N3 * E) >> 2;   // 1,835,008
    const long stride = (long)gridDim.x * 256;
    for (long i4 = (long)blockIdx.x * 256 + threadIdx.x; i4 < total4; i4 += stride) {
        const long e = i4 * 4;
        const float* src;
        __bf16* dst;
        if (e < (long)M * E) { src = x + e; dst = xb + e; }
        else {
            const long e2 = e - (long)M * E;
            const int which = (int)(e2 >> 20);
            const long off  = e2 & ((1L << 20) - 1);
            src = (which == 0 ? Wk : which == 1 ? Wv : Wq) + off;
            dst = wall + e2;
        }
        float4 f = *reinterpret_cast<const float4*>(src);
        bf16x4 o;
        o[0] = (__bf16)f.x; o[1] = (__bf16)f.y; o[2] = (__bf16)f.z; o[3] = (__bf16)f.w;
        *reinterpret_cast<bf16x4*>(dst) = o;
    }
}

// ---------------- QKV GEMM v7 (R10-verified): DMA core + coalesced epilogues ----------------
// bf16 input, triple-buffer distance-2 counted vmcnt(4) (never 0 in steady
// state), raw s_barrier. No setprio here: m190 shows setprio is null/negative
// on barrier-lockstep GEMM waves.
__global__ __launch_bounds__(256, 3)
void qkv_gemm(const __bf16* __restrict__ xb, const __bf16* __restrict__ wall,
              const float* __restrict__ theta, __bf16* __restrict__ kvq) {
    __shared__ __align__(1024) __bf16 smem[6 * 128 * 32];   // A0|A1|A2|B0|B1|B2 = 48 KB
    __bf16* tile = smem;   // epilogue alias: V: 128x128; K/Q: 128x132 = 33 KB

    const int t    = threadIdx.x;
    const int lane = t & 63;
    const int w    = t >> 6;
    const int quad = lane >> 4;
    const int l16  = lane & 15;
    const int wm   = w >> 1, wn = w & 1;      // 2x2 wave grid, 64x64 each

    // 2D XCD-locality remap (neutral in R9 but harmless; grid = 768 blocks)
    const int id   = blockIdx.x;
    const int xcd  = id & 7;
    const int lid  = id >> 3;                 // 0..95 within this XCD
    const int lr   = lid / 12, lc0 = lid % 12;
    const int mbase = ((xcd >> 1) * 8 + lr) * 128;
    const int nbase = ((xcd & 1) * 12 + lc0) * 128;

    f32x4 acc[4][4];
    #pragma unroll
    for (int i = 0; i < 4; i++)
        #pragma unroll
        for (int j = 0; j < 4; j++)
            acc[i][j] = f32x4{0.f, 0.f, 0.f, 0.f};

    const int srow = lane >> 2;
    const int srcc = (lane & 3) ^ ((lane >> 3) & 3);
    const __bf16* ga = xb   + (long)(mbase + srow) * E + srcc * 8;
    const __bf16* gb = wall + (long)(nbase + srow) * E + srcc * 8;

    const int csw = (l16 >> 1) & 3;

    // prologue: tiles 0 and 1 into buffers 0 and 1 (8 loads outstanding)
    #pragma unroll
    for (int pt = 0; pt < 2; pt++) {
        #pragma unroll
        for (int c = 0; c < 2; c++) {
            async16(smem + pt * 4096 +         (c * 64 + w * 16) * 32,
                    ga + (long)(c * 64 + w * 16) * E + pt * 32);
            async16(smem + pt * 4096 + 12288 + (c * 64 + w * 16) * 32,
                    gb + (long)(c * 64 + w * 16) * E + pt * 32);
        }
    }

    int cur = 0;
    constexpr int ITERS = E / 32;   // 32
    for (int it = 0; it < ITERS; it++) {
        if (it < ITERS - 1) asm volatile("s_waitcnt vmcnt(4)" ::: "memory");
        else                asm volatile("s_waitcnt vmcnt(0)" ::: "memory");
        asm volatile("s_barrier" ::: "memory");   // raw: no drain

        if (it + 2 < ITERS) {
            const int pb  = (cur == 0) ? 2 : cur - 1;
            const int kk2 = (it + 2) * 32;
            #pragma unroll
            for (int c = 0; c < 2; c++) {
                async16(smem + pb * 4096 +         (c * 64 + w * 16) * 32,
                        ga + (long)(c * 64 + w * 16) * E + kk2);
                async16(smem + pb * 4096 + 12288 + (c * 64 + w * 16) * 32,
                        gb + (long)(c * 64 + w * 16) * E + kk2);
            }
        }

        const __bf16* Asb = smem + cur * 4096;
        const __bf16* Bsb = smem + cur * 4096 + 12288;
        bf16x8 a[4], b[4];
        #pragma unroll
        for (int i = 0; i < 4; i++)
            a[i] = *reinterpret_cast<const bf16x8*>(
                &Asb[(wm * 64 + i * 16 + l16) * 32 + (quad ^ csw) * 8]);
        #pragma unroll
        for (int j = 0; j < 4; j++)
            b[j] = *reinterpret_cast<const bf16x8*>(
                &Bsb[(wn * 64 + j * 16 + l16) * 32 + (quad ^ csw) * 8]);
        #pragma unroll
        for (int i = 0; i < 4; i++)
            #pragma unroll
            for (int j = 0; j < 4; j++)
                acc[i][j] = __builtin_amdgcn_mfma_f32_16x16x32_bf16(a[i], b[j], acc[i][j], 0, 0, 0);

        cur = (cur == 2) ? 0 : cur + 1;
    }

    const int region = nbase >> 10;           // block-uniform 0=K 1=V 2=Q
    const int bb = mbase >> 11;
    __syncthreads();                          // drain staging reads before aliasing smem
    if (region == 1) {
        // ---- V: transposed tile -> V^T [B,H,DK,S] ----
        #pragma unroll
        for (int i = 0; i < 4; i++) {
            const int cchunk = wm * 8 + i * 2 + (quad >> 1);
            #pragma unroll
            for (int j = 0; j < 4; j++) {
                const int cirb = wn * 64 + j * 16 + l16;
                const int cs = cchunk ^ l16;
                bf16x4 pk;
                #pragma unroll
                for (int r = 0; r < 4; r++) pk[r] = (__bf16)acc[i][j][r];
                *reinterpret_cast<bf16x4*>(&tile[cirb * 128 + cs * 8 + (quad & 1) * 4]) = pk;
            }
        }
        __syncthreads();
        const int h0 = (nbase & 1023) >> 6;
        __bf16* vt = kvq + RSZ;               // V^T region: [B,H,DK,S]
        #pragma unroll
        for (int p = 0; p < 8; p++) {
            const int dcol = p * 16 + (t >> 4);
            const int lc = t & 15;
            const int cs2 = lc ^ (dcol & 15);
            bf16x8 vv = *reinterpret_cast<const bf16x8*>(&tile[dcol * 128 + cs2 * 8]);
            const int hh = h0 + (dcol >> 6), d = dcol & 63;
            *reinterpret_cast<bf16x8*>(
                &vt[((long)(bb * H + hh) * DK + d) * S + (mbase & 2047) + lc * 8]) = vv;
        }
    } else {
        // ---- K/Q: [s][d] tile (stride 132) -> coalesced 16B stores ----
        __bf16* dst = kvq + (region == 2 ? 2 * RSZ : 0);
        float th[4];
        if (region == 2) {
            #pragma unroll
            for (int j = 0; j < 4; j++) th[j] = theta[j * 16 + l16];
        }
        #pragma unroll
        for (int i = 0; i < 4; i++) {
            #pragma unroll
            for (int j = 0; j < 4; j++) {
                const int c = wn * 64 + j * 16 + l16;
                #pragma unroll
                for (int r = 0; r < 4; r++) {
                    const int cir = wm * 64 + i * 16 + quad * 4 + r;
                    float v = acc[i][j][r];
                    if (region == 2) v = cosf(v + th[j]) * QSCALE;  // fold 1/sqrt(DK)*log2e
                    tile[cir * 132 + c] = (__bf16)v;
                }
            }
        }
        __syncthreads();
        const int h0 = (nbase & 1023) >> 6;
        #pragma unroll
        for (int p = 0; p < 8; p++) {
            const int row = p * 16 + (t >> 4);   // 0..127 (within-block s)
            const int lc  = t & 15;              // 8-elem chunk along d
            bf16x8 vv = *reinterpret_cast<const bf16x8*>(&tile[row * 132 + lc * 8]);
            const int s = (mbase + row) & 2047;
            const int h = h0 + (lc >> 3), d = (lc & 7) * 8;
            *reinterpret_cast<bf16x8*>(
                &dst[((long)(bb * H + h) * S + s) * DK + d]) = vv;
        }
    }
}

// ---------------- attention v16: v15 + s_setprio around MFMA clusters (T5) ----------------
// Loop/staging/softmax/epilogue identical to R12-verified v15 (53.1-53.3us).
// T5: the 2 blocks/CU are INDEPENDENT (different bh, no shared barrier) ->
// m191's measured +4-7% regime (m190's null was lockstep-GEMM waves).
__global__ __launch_bounds__(256, 2)
void attn_kernel(const __bf16* __restrict__ q_ws, const __bf16* __restrict__ k_ws,
                 const __bf16* __restrict__ v_ws, float* __restrict__ out) {
    __shared__ __align__(1024) __bf16 Ks[3][64 * 64];   // [key][d] swizzled, 8 KB each
    __shared__ __align__(1024) __bf16 Vs[3][64 * 64];   // [d][key] swizzled, 8 KB each
    __shared__ __align__(16)   __bf16 Pl[4][32 * 72];   // per-wave P [qrow][key], stride 72
    __shared__ __align__(16)   float  ls_lds[4][32];

    const int lane = threadIdx.x & 63;
    const int w    = threadIdx.x >> 6;          // 0..3
    const int quad = lane >> 4;
    const int l16  = lane & 15;

    // XCD swizzle: 4 bh per id%8 class -> per-XCD K/V set 2MB < 4MB L2 (R6-verified)
    const int id    = blockIdx.x;
    const int bh    = (id & 7) + 8 * ((id >> 3) & 3);
    const int qbase = (id >> 5) * 128 + w * 32;  // wave owns 32 q-rows

    const __bf16* qp = q_ws + (long)bh * S * DK;
    const __bf16* kp = k_ws + (long)bh * S * DK;
    const __bf16* vp = v_ws + (long)bh * DK * S;   // [DK][S]

    // staging: 8 rows x 8 chunks(16B) per async16; source chunk XOR-swizzled
    const int sr  = lane >> 3;
    const int scs = (lane & 7) ^ sr;

    // Q B-frags resident: B[k=d=ks*32+quad*8+j][n=qrow=nt*16+l16]
    bf16x8 bq[2][2];
    #pragma unroll
    for (int nt = 0; nt < 2; nt++)
        #pragma unroll
        for (int ks = 0; ks < 2; ks++)
            bq[nt][ks] = *reinterpret_cast<const bf16x8*>(
                qp + (long)(qbase + nt * 16 + l16) * DK + ks * 32 + quad * 8);

    f32x4 o[2][4];     // O[qrow-tile mt][d-tile nt]
    #pragma unroll
    for (int i = 0; i < 2; i++)
        #pragma unroll
        for (int j = 0; j < 4; j++) o[i][j] = f32x4{0.f, 0.f, 0.f, 0.f};
    float lsum[2] = {0.f, 0.f};   // per-lane partial row sums, qrow = nt*16+l16

    // prologue: tiles 0,1 into buffers 0,1 — 4 DMA issues per tile per wave
    #pragma unroll
    for (int pt = 0; pt < 2; pt++) {
        #pragma unroll
        for (int i = 0; i < 2; i++) {
            const int row = w * 16 + i * 8;
            async16(&Ks[pt][row * 64], kp + (long)(pt * 64 + row + sr) * DK + scs * 8);
            async16(&Vs[pt][row * 64], vp + (long)(row + sr) * S + pt * 64 + scs * 8);
        }
    }

    int cur = 0;
    constexpr int ITERS = S / 64;   // 32
    for (int it = 0; it < ITERS; it++) {
        if (it < ITERS - 1) asm volatile("s_waitcnt vmcnt(4)" ::: "memory");
        else                asm volatile("s_waitcnt vmcnt(0)" ::: "memory");
        asm volatile("s_barrier" ::: "memory");   // raw: no drain

        if (it + 2 < ITERS) {
            const int kt2 = (it + 2) * 64;
            const int pb  = (cur == 0) ? 2 : cur - 1;
            #pragma unroll
            for (int i = 0; i < 2; i++) {
                const int row = w * 16 + i * 8;
                async16(&Ks[pb][row * 64], kp + (long)(kt2 + row + sr) * DK + scs * 8);
                async16(&Vs[pb][row * 64], vp + (long)(row + sr) * S + kt2 + scs * 8);
            }
        }

        // ---- S^T = K Q^T : C[key(regs) 64][qrow(lanes) 32] ----
        f32x4 sacc[4][2];  // [key-tile mt][qrow-tile nt]
        #pragma unroll
        for (int i = 0; i < 4; i++)
            #pragma unroll
            for (int j = 0; j < 2; j++) sacc[i][j] = f32x4{0.f, 0.f, 0.f, 0.f};
        #pragma unroll
        for (int ks = 0; ks < 2; ks++) {
            bf16x8 ak[4];
            #pragma unroll
            for (int mt = 0; mt < 4; mt++)
                ak[mt] = *reinterpret_cast<const bf16x8*>(
                    &Ks[cur][(mt * 16 + l16) * 64 + ((ks * 4 + quad) ^ (l16 & 7)) * 8]);
            __builtin_amdgcn_s_setprio(1);
            #pragma unroll
            for (int mt = 0; mt < 4; mt++)
                #pragma unroll
                for (int nt = 0; nt < 2; nt++)
                    sacc[mt][nt] = __builtin_amdgcn_mfma_f32_16x16x32_bf16(
                        ak[mt], bq[nt][ks], sacc[mt][nt], 0, 0, 0);
            __builtin_amdgcn_s_setprio(0);
        }

        // ---- P = exp2(S^T): 4 consecutive keys (regs) -> one b64 store ----
        #pragma unroll
        for (int mt = 0; mt < 4; mt++)
            #pragma unroll
            for (int nt = 0; nt < 2; nt++) {
                float p0 = __builtin_amdgcn_exp2f(sacc[mt][nt][0]);
                float p1 = __builtin_amdgcn_exp2f(sacc[mt][nt][1]);
                float p2 = __builtin_amdgcn_exp2f(sacc[mt][nt][2]);
                float p3 = __builtin_amdgcn_exp2f(sacc[mt][nt][3]);
                lsum[nt] += (p0 + p1) + (p2 + p3);
                bf16x4 pk;
                pk[0] = (__bf16)p0; pk[1] = (__bf16)p1;
                pk[2] = (__bf16)p2; pk[3] = (__bf16)p3;
                *reinterpret_cast<bf16x4*>(
                    &Pl[w][(nt * 16 + l16) * 72 + mt * 16 + quad * 4]) = pk;
            }

        // ---- O += P V : A=P[m=qrow][k=key], B=V[k=key][n=d], 2 k-halves ----
        #pragma unroll
        for (int kh = 0; kh < 2; kh++) {
            bf16x8 bv[4];
            #pragma unroll
            for (int nt = 0; nt < 4; nt++)
                bv[nt] = *reinterpret_cast<const bf16x8*>(
                    &Vs[cur][(nt * 16 + l16) * 64 + ((kh * 4 + quad) ^ (l16 & 7)) * 8]);
            __builtin_amdgcn_s_setprio(1);
            #pragma unroll
            for (int mt = 0; mt < 2; mt++) {
                bf16x8 ap = *reinterpret_cast<const bf16x8*>(
                    &Pl[w][(mt * 16 + l16) * 72 + kh * 32 + quad * 8]);
                #pragma unroll
                for (int nt = 0; nt < 4; nt++)
                    o[mt][nt] = __builtin_amdgcn_mfma_f32_16x16x32_bf16(
                        ap, bv[nt], o[mt][nt], 0, 0, 0);
            }
            __builtin_amdgcn_s_setprio(0);
        }

        cur = (cur == 2) ? 0 : cur + 1;
    }

    // ---- finalize l: reduce partials across the 4 quads, broadcast via LDS ----
    #pragma unroll
    for (int nt = 0; nt < 2; nt++) {
        float v = lsum[nt];
        v += __shfl_xor(v, 16);
        v += __shfl_xor(v, 32);
        ls_lds[w][nt * 16 + l16] = v;   // quads duplicate-write same value (benign)
    }

    // ---- epilogue: per-wave LDS bounce -> coalesced f32x4 stores ----
    __syncthreads();   // all waves done reading Ks/Vs (loop fully consumed)
    float* scr = (w < 3) ? (float*)&Ks[w][0] : (float*)&Vs[0][0];  // 8 KB = 32x64 f32
    const int b = bh >> 4, h = bh & 15;
    #pragma unroll
    for (int mt = 0; mt < 2; mt++) {
        f32x4 lv = *reinterpret_cast<const f32x4*>(&ls_lds[w][mt * 16 + quad * 4]);
        #pragma unroll
        for (int r = 0; r < 4; r++) {
            const float inv = 1.0f / lv[r];
            const int row = mt * 16 + quad * 4 + r;       // 0..31 within wave
            #pragma unroll
            for (int nt = 0; nt < 4; nt++)
                scr[row * 64 + nt * 16 + l16] = o[mt][nt][r] * inv;
        }
    }
    __syncthreads();   // order scr writes before aliased reads
    #pragma unroll
    for (int p = 0; p < 8; p++) {
        const int c = p * 64 + lane;
        const int row = c >> 4, chunk = c & 15;           // row 0..31, 16B chunk 0..15
        f32x4 v4 = *reinterpret_cast<const f32x4*>(&scr[row * 64 + chunk * 4]);
        const int srow = qbase + row;
        *reinterpret_cast<f32x4*>(
            &out[(long)(b * S + srow) * E + h * DK + chunk * 4]) = v4;
    }
}

extern "C" void kernel_launch(void* const* d_in, const int* in_sizes, int n_in,
                              void* d_out, int out_size, void* d_ws, size_t ws_size,
                              hipStream_t stream) {
    const float* x     = (const float*)d_in[0];
    const float* Wk    = (const float*)d_in[1];
    const float* Wv    = (const float*)d_in[2];
    const float* Wq    = (const float*)d_in[3];
    const float* theta = (const float*)d_in[4];
    float* out = (float*)d_out;

    // ws: kvq[3*RSZ: K | V^T | Q] -- 25.2 MB. d_out doubles as scratch for
    // xb (8.4 MB) + wall (6.3 MB) during cvt+qkv; attn fully overwrites it.
    __bf16* kvq  = (__bf16*)d_ws;
    __bf16* k_ws = kvq;
    __bf16* v_t  = kvq + RSZ;
    __bf16* q_ws = kvq + 2 * RSZ;
    __bf16* xb   = (__bf16*)d_out;
    __bf16* wall = xb + (long)M * E;

    dim3 blk(256);
    cvt_kernel<<<dim3(1792), blk, 0, stream>>>(x, Wk, Wv, Wq, xb, wall);
    qkv_gemm<<<dim3(768), blk, 0, stream>>>(xb, wall, theta, kvq);
    attn_kernel<<<dim3(512), blk, 0, stream>>>(q_ws, k_ws, v_t, out);
}